// Round 1
// baseline (91.149 us; speedup 1.0000x reference)
//
#include <hip/hip_runtime.h>

#define B_ 16
#define IN_ 1024
#define OUT_ 1024
#define G_ 8
#define OTILE 64
#define ITILE 32
#define NOT_ (OUT_/OTILE)   // 16 o-tiles
#define NIT_ (IN_/ITILE)    // 32 i-tiles

__device__ __forceinline__ float rcp_f(float x) { return __builtin_amdgcn_rcpf(x); }

// block = 256 threads = 4 waves; thread owns one o (lane) and 8 i's (quarter q).
// sigmoid(x+g) = 1/(1 + E*F), E = exp2(-x*log2e) staged in LDS, F = exp2(-g*log2e).
// Pairs of terms combined into one rational, two pairs share one rcp each:
//   1/(1+eF0)+1/(1+eF1) = (2+eS)/(1+eS+e^2 P),  S=F0+F1, P=F0*F1  (exact algebra)
__global__ __launch_bounds__(256, 2) void kan_main(
    const float* __restrict__ x,
    const float* __restrict__ W,
    const float* __restrict__ gridp,
    float* __restrict__ out)
{
    __shared__ float xs[B_][ITILE];
    __shared__ float es[B_][ITILE];
    __shared__ float red[4][B_][OTILE];

    const int tid  = threadIdx.x;
    const int ot   = blockIdx.x & (NOT_-1);
    const int it   = blockIdx.x / NOT_;
    const int i0   = it * ITILE;
    const int lane = tid & 63;
    const int q    = tid >> 6;
    const int o    = ot * OTILE + lane;

    const float NL2E = -1.44269504088896340736f;

    // Stage x tile and E = exp(-x) into LDS (512 values, 2 per thread).
    for (int k = tid; k < B_*ITILE; k += 256) {
        const int b  = k >> 5;      // / ITILE
        const int il = k & 31;      // % ITILE
        const float xv = x[b*IN_ + i0 + il];
        xs[b][il] = xv;
        es[b][il] = exp2f(NL2E * xv);
    }
    __syncthreads();

    float acc[B_];
    #pragma unroll
    for (int b = 0; b < B_; ++b) acc[b] = 0.0f;

    const int ibase = i0 + q * 8;   // 8 i's per quarter
    const float* gp = gridp + (size_t)ibase * (OUT_*G_) + (size_t)o * G_;
    const float* wp = W + (size_t)o * IN_ + ibase;

    // base-weight values for this thread's 8 i's (32B-aligned)
    float4 w0 = *(const float4*)(wp);
    float4 w1 = *(const float4*)(wp + 4);
    float wv[8] = {w0.x, w0.y, w0.z, w0.w, w1.x, w1.y, w1.z, w1.w};

    for (int ii = 0; ii < 8; ++ii) {
        const int il = q*8 + ii;
        float4 ga = *(const float4*)(gp + (size_t)ii * (OUT_*G_));
        float4 gb = *(const float4*)(gp + (size_t)ii * (OUT_*G_) + 4);
        const float F0 = exp2f(NL2E * ga.x);
        const float F1 = exp2f(NL2E * ga.y);
        const float F2 = exp2f(NL2E * ga.z);
        const float F3 = exp2f(NL2E * ga.w);
        const float F4 = exp2f(NL2E * gb.x);
        const float F5 = exp2f(NL2E * gb.y);
        const float F6 = exp2f(NL2E * gb.z);
        const float F7 = exp2f(NL2E * gb.w);
        // per-pair sums/products, shared across all 16 batches
        const float S0 = F0 + F1, P0 = F0 * F1;
        const float S1 = F2 + F3, P1 = F2 * F3;
        const float S2 = F4 + F5, P2 = F4 * F5;
        const float S3 = F6 + F7, P3 = F6 * F7;
        const float wvi = wv[ii];
        #pragma unroll
        for (int b = 0; b < B_; ++b) {
            const float e  = es[b][il];   // wave-uniform LDS broadcast
            const float xv = xs[b][il];
            const float e2 = e * e;
            // pair p: t = 1 + e*S_p ; num = t + 1 ; den = t + e2*P_p
            float t0 = fmaf(e, S0, 1.0f), n0 = t0 + 1.0f, d0 = fmaf(e2, P0, t0);
            float t1 = fmaf(e, S1, 1.0f), n1 = t1 + 1.0f, d1 = fmaf(e2, P1, t1);
            float t2 = fmaf(e, S2, 1.0f), n2 = t2 + 1.0f, d2 = fmaf(e2, P2, t2);
            float t3 = fmaf(e, S3, 1.0f), n3 = t3 + 1.0f, d3 = fmaf(e2, P3, t3);
            // quad combine: two rationals -> one rcp each
            float na = fmaf(n0, d1, n1 * d0);
            float da = d0 * d1;
            float nb = fmaf(n2, d3, n3 * d2);
            float db = d2 * d3;
            float s  = fmaf(na, rcp_f(da), nb * rcp_f(db));
            acc[b] += fmaf(xv, wvi, s);   // fused base matmul + spline sum
        }
    }

    // reduce the 4 quarter-waves in LDS, then one atomic per (b, o)
    #pragma unroll
    for (int b = 0; b < B_; ++b) red[q][b][lane] = acc[b];
    __syncthreads();
    for (int k = tid; k < B_*OTILE; k += 256) {
        const int b  = k >> 6;
        const int ol = k & 63;
        const float v = red[0][b][ol] + red[1][b][ol] + red[2][b][ol] + red[3][b][ol];
        atomicAdd(out + b*OUT_ + ot*OTILE + ol, v);
    }
}

extern "C" void kernel_launch(void* const* d_in, const int* in_sizes, int n_in,
                              void* d_out, int out_size, void* d_ws, size_t ws_size,
                              hipStream_t stream) {
    const float* x  = (const float*)d_in[0];     // [16, 1024]
    const float* W  = (const float*)d_in[1];     // [1024, 1024]
    const float* gp = (const float*)d_in[2];     // [1024, 1024, 8]
    float* out = (float*)d_out;                  // [16, 1024]

    hipMemsetAsync(out, 0, (size_t)B_ * OUT_ * sizeof(float), stream);
    kan_main<<<dim3(NOT_ * NIT_), dim3(256), 0, stream>>>(x, W, gp, out);
}